// Round 6
// baseline (402.623 us; speedup 1.0000x reference)
//
#include <hip/hip_runtime.h>
#include <hip/hip_bf16.h>
#include <stdint.h>

typedef unsigned int u32;
typedef unsigned short u16;
typedef float v2f __attribute__((ext_vector_type(2)));
typedef short bf16x8 __attribute__((ext_vector_type(8)));
typedef float f32x4 __attribute__((ext_vector_type(4)));

#define LN_EPS_ 1e-5f
#define EPS_ 1e-8f

__device__ __forceinline__ float bflo(u32 v){ return __uint_as_float(v << 16); }
__device__ __forceinline__ float bfhi(u32 v){ return __uint_as_float(v & 0xFFFF0000u); }
__device__ __forceinline__ u32 f2bf(float f){
    u32 x = __float_as_uint(f);
    return (x + 0x7FFFu + ((x >> 16) & 1u)) >> 16;
}
__device__ __forceinline__ u32 pack2bf(float a, float b){
    union { __hip_bfloat162 h; u32 u; } cv;
    cv.h = __float22bfloat162_rn(float2{a, b});
    return cv.u;
}
// packed fp32 math (gfx90a+/gfx950): 2 MACs per instruction
__device__ __forceinline__ v2f pkfma(v2f a, v2f b, v2f c){
    v2f d; asm("v_pk_fma_f32 %0, %1, %2, %3" : "=v"(d) : "v"(a), "v"(b), "v"(c)); return d;
}
__device__ __forceinline__ v2f pkadd(v2f a, v2f b){
    v2f d; asm("v_pk_add_f32 %0, %1, %2" : "=v"(d) : "v"(a), "v"(b)); return d;
}
__device__ __forceinline__ bf16x8 as_bf16x8(uint4 u){
    union { uint4 a; bf16x8 b; } c; c.a = u; return c.b;
}

// ---------------- kernel P: one-time weight prep ---------------------------
__global__ __launch_bounds__(256) void k_pack(
    const float* __restrict__ Wq, const float* __restrict__ Wv,
    const float* __restrict__ Wih, const float* __restrict__ Whh,
    const float* __restrict__ w1, const float* __restrict__ w2,
    float* __restrict__ WqT, u32* __restrict__ Pv, u32* __restrict__ Pih,
    u32* __restrict__ Phh, u32* __restrict__ Pw1, u32* __restrict__ Pw2,
    u32* __restrict__ Rg32)
{
    int i = blockIdx.x * 256 + threadIdx.x;
    if (i < 8192) {                                   // Pv
        int dp = i >> 7, o = i & 127;
        Pv[i] = pack2bf(Wv[o * 128 + 2 * dp], Wv[o * 128 + 2 * dp + 1]);
    } else if (i < 32768) {                           // Pih
        int r = i - 8192; int dp = r / 384, j = r - dp * 384;
        Pih[r] = pack2bf(Wih[j * 128 + 2 * dp], Wih[j * 128 + 2 * dp + 1]);
    } else if (i < 57344) {                           // Phh
        int r = i - 32768; int dp = r / 384, j = r - dp * 384;
        Phh[r] = pack2bf(Whh[j * 128 + 2 * dp], Whh[j * 128 + 2 * dp + 1]);
    } else if (i < 73728) {                           // Pw1
        int r = i - 57344; int dp = r >> 8, j = r & 255;
        Pw1[r] = pack2bf(w1[j * 128 + 2 * dp], w1[j * 128 + 2 * dp + 1]);
    } else if (i < 90112) {                           // Pw2
        int r = i - 73728; int mp = r >> 7, o = r & 127;
        Pw2[r] = pack2bf(w2[o * 256 + 2 * mp], w2[o * 256 + 2 * mp + 1]);
    } else if (i < 106496) {                          // WqT fp32
        int r = i - 90112; int d = r >> 7, o = r & 127;
        WqT[r] = Wq[o * 128 + d];
    } else if (i < 143360) {                          // zero Rg rows 7..15
        int r = i - 106496; int b = r / 576, rem = r - b * 576;
        Rg32[b * 1024 + 448 + rem] = 0;
    }
}

// ---------------- kernel 0: slots init + prep for iter 0 (256 thr) --------
__global__ __launch_bounds__(256) void k_init_prep(
    const float* __restrict__ slots_init, const float* __restrict__ mu,
    const float* __restrict__ ls, float* __restrict__ slots,
    const float* __restrict__ g_s, const float* __restrict__ b_s,
    const float* __restrict__ WqT, const float* __restrict__ Wk,
    const float* __restrict__ g_in, const float* __restrict__ b_in,
    u16* __restrict__ Rg, float* __restrict__ c1ws, float* __restrict__ c2ws)
{
    __shared__ float snb[128], qb[128], xch[128], red4[4];
    int bs = blockIdx.x, t = threadIdx.x;
    int b = bs / 7, s = bs - b * 7;
    int h = t & 127, half = t >> 7;
    float nv = 0.f;
    if (!half) {
        nv = mu[h] + expf(ls[h]) * slots_init[bs * 132 + h];
        slots[bs * 128 + h] = nv;
    }
    // LN stats
    if (!half) {
        float smv = nv, sqv = nv * nv;
        for (int m = 32; m >= 1; m >>= 1) { smv += __shfl_xor(smv, m); sqv += __shfl_xor(sqv, m); }
        if ((t & 63) == 0) { red4[(t >> 6) * 2] = smv; red4[(t >> 6) * 2 + 1] = sqv; }
    }
    __syncthreads();
    float mean = (red4[0] + red4[2]) * (1.0f / 128.0f);
    float var  = (red4[1] + red4[3]) * (1.0f / 128.0f) - mean * mean;
    float rsv = rsqrtf(var + LN_EPS_);
    if (!half) snb[h] = (nv - mean) * rsv * g_s[h] + b_s[h];
    __syncthreads();
    {
        float q0 = 0.f, q1 = 0.f;
        int d0 = half * 64;
        #pragma unroll 4
        for (int d = d0; d < d0 + 64; d += 2) {
            q0 += WqT[d * 128 + h] * snb[d];
            q1 += WqT[(d + 1) * 128 + h] * snb[d + 1];
        }
        if (half) xch[h] = q0 + q1;
        __syncthreads();
        if (!half) qb[h] = q0 + q1 + xch[h];
        __syncthreads();
    }
    float r0 = 0.f, r1 = 0.f;
    int j0 = half * 64;
    #pragma unroll 4
    for (int j = j0; j < j0 + 64; j += 2) {
        r0 += Wk[j * 128 + h] * qb[j];
        r1 += Wk[(j + 1) * 128 + h] * qb[j + 1];
    }
    if (half) xch[h] = r0 + r1;
    __syncthreads();
    if (!half) {
        float r = (r0 + r1 + xch[h]) * 0.08838834764831845f;   // 128^-0.5
        float rt  = g_in[h] * r;
        float c2v = b_in[h] * r;
        Rg[((size_t)b * 16 + s) * 128 + h] = (u16)f2bf(rt);
        float c1p = rt, c2p = c2v;
        for (int m = 32; m >= 1; m >>= 1) { c1p += __shfl_xor(c1p, m); c2p += __shfl_xor(c2p, m); }
        if ((t & 63) == 0) { red4[(t >> 6) * 2] = c1p; red4[(t >> 6) * 2 + 1] = c2p; }
    }
    __syncthreads();
    if (t == 0) {
        c1ws[b * 8 + s] = red4[0] + red4[2];
        c2ws[b * 8 + s] = red4[1] + red4[3];
    }
}

// ---------------- kernel 2: streaming attention (64-row tile, 8 blk/CU) ----
// it=0: read fp32 X, pack+stats, store swizzled bf16 tile image + stats to
//       global (X is iteration-invariant; only R changes).
// it>0: load tile image + stats verbatim (L3-resident, ~16KB/block).
// phase1: MFMA 16x16x32_bf16, softmax in C-frag layout.
// phase2: n-paired pkfma -> plain coalesced float2 partial stores (no atomics).
__global__ __launch_bounds__(256, 8) void k_attn(
    const float* __restrict__ xin,
    const u16* __restrict__ Rg, const float* __restrict__ c1ws,
    const float* __restrict__ c2ws,
    float* __restrict__ ypart, float* __restrict__ Zp, float* __restrict__ Ap,
    u32* __restrict__ Xbf, float* __restrict__ Sg, int first)
{
    __shared__ u32 tile[4096];          // 16 KB
    __shared__ __align__(16) float wt[448];   // w fp32 [s][n] (n local 0..63)
    __shared__ __align__(8)  float stats[128];// (mean, rs) per row
    __shared__ float c1l[16], c2l[16];
    __shared__ float redp[4][8], redw[4][8];
    int t = threadIdx.x;
    int b = blockIdx.y;
    int n0 = blockIdx.x * 64;
    int lane = t & 63, wv = t >> 6;
    int ls = lane & 15, lg = lane >> 4;
    size_t blk = (size_t)b * 64 + blockIdx.x;

    if (t < 16) {
        c1l[t] = (t < 7) ? c1ws[b * 8 + t] : 0.f;
        c2l[t] = (t < 7) ? c2ws[b * 8 + t] : 0.f;
    }

    // B-fragments (R) straight from global into VGPRs, reused all tiles
    bf16x8 bfr[4];
    {
        const u16* Rrow = Rg + ((size_t)b * 16 + ls) * 128;
        #pragma unroll
        for (int kk = 0; kk < 4; kk++)
            bfr[kk] = as_bf16x8(*(const uint4*)&Rrow[kk * 32 + lg * 8]);
    }

    if (first) {
        // ---- pack + row stats from fp32 X ----
        int r = t >> 2, p = t & 3;
        const float4* xg = (const float4*)(xin + ((size_t)b * 4096 + n0 + r) * 128 + p * 32);
        v2f smp = (v2f){0.f, 0.f}, sqp = (v2f){0.f, 0.f};
        #pragma unroll
        for (int i = 0; i < 8; i++) {
            float4 v = xg[i];
            v2f lo = (v2f){v.x, v.y}, hi = (v2f){v.z, v.w};
            smp = pkadd(smp, pkadd(lo, hi));
            sqp = pkfma(lo, lo, sqp);
            sqp = pkfma(hi, hi, sqp);
            int q = p * 4 + (i >> 1), rem = (i & 1) * 2;
            *(uint2*)&tile[(r * 16 + (q ^ (r & 15))) * 4 + rem] =
                make_uint2(pack2bf(v.x, v.y), pack2bf(v.z, v.w));
        }
        float sm = smp.x + smp.y, sq = sqp.x + sqp.y;
        sm += __shfl_xor(sm, 1); sq += __shfl_xor(sq, 1);
        sm += __shfl_xor(sm, 2); sq += __shfl_xor(sq, 2);
        if (!p) {
            float mean = sm * (1.0f / 128.0f);
            float var  = sq * (1.0f / 128.0f) - mean * mean;
            *(float2*)&stats[2 * r] = make_float2(mean, rsqrtf(var + LN_EPS_));
        }
        __syncthreads();
        // persist tile image + stats for iterations 1,2
        uint4* dst = (uint4*)(Xbf + blk * 4096);
        const uint4* srcT = (const uint4*)tile;
        #pragma unroll
        for (int j = 0; j < 4; j++) dst[j * 256 + t] = srcT[j * 256 + t];
        if (t < 128) Sg[blk * 128 + t] = stats[t];
    } else {
        // ---- verbatim reload (L3-resident bf16 image) ----
        uint4* dstT = (uint4*)tile;
        const uint4* src = (const uint4*)(Xbf + blk * 4096);
        #pragma unroll
        for (int j = 0; j < 4; j++) dstT[j * 256 + t] = src[j * 256 + t];
        if (t < 128) stats[t] = Sg[blk * 128 + t];
        __syncthreads();
    }

    // ---- phase1: MFMA logits (one 16-row fragment per wave) ----
    f32x4 acc0 = {0.f, 0.f, 0.f, 0.f};
    {
        int m0 = wv * 16 + ls;
        #pragma unroll
        for (int kk = 0; kk < 4; kk++) {
            int q = kk * 4 + lg;
            bf16x8 a0 = as_bf16x8(*(const uint4*)&tile[(m0 * 16 + (q ^ ls)) * 4]);
            acc0 = __builtin_amdgcn_mfma_f32_16x16x32_bf16(a0, bfr[kk], acc0, 0, 0, 0);
        }
    }
    // ---- softmax epilogue in C-frag layout ----
    {
        float zsum = 0.f, asum = 0.f;
        float c1v = c1l[ls], c2v = c2l[ls];
        bool sv = ls < 7;
        int nbase = wv * 16 + lg * 4;
        #pragma unroll
        for (int r4 = 0; r4 < 4; r4++) {
            int n = nbase + r4;
            float2 stf = *(const float2*)&stats[2 * n];
            float L = sv ? (stf.y * (acc0[r4] - stf.x * c1v) + c2v) : -3.4e38f;
            float mx = L;
            mx = fmaxf(mx, __shfl_xor(mx, 1));
            mx = fmaxf(mx, __shfl_xor(mx, 2));
            mx = fmaxf(mx, __shfl_xor(mx, 4));
            mx = fmaxf(mx, __shfl_xor(mx, 8));
            float e = __expf(L - mx);
            float ssum = e;
            ssum += __shfl_xor(ssum, 1);
            ssum += __shfl_xor(ssum, 2);
            ssum += __shfl_xor(ssum, 4);
            ssum += __shfl_xor(ssum, 8);
            float p = e * (1.0f / ssum) + EPS_;
            float w = p * stf.y;
            if (sv) {
                wt[ls * 64 + n] = w;
                zsum += p;
                asum += w * stf.x;
            }
        }
        zsum += __shfl_xor(zsum, 16); zsum += __shfl_xor(zsum, 32);
        asum += __shfl_xor(asum, 16); asum += __shfl_xor(asum, 32);
        if (lane < 7) { redp[wv][lane] = zsum; redw[wv][lane] = asum; }
    }
    __syncthreads();
    if (t < 7)
        Zp[blk * 8 + t] = redp[0][t] + redp[1][t] + redp[2][t] + redp[3][t];
    else if (t >= 64 && t < 71) {
        int s = t - 64;
        Ap[blk * 8 + s] = redw[0][s] + redw[1][s] + redw[2][s] + redw[3][s];
    }

    // ---- phase2 ----
    int nh = t >> 7, dp = t & 63, sA = (t >> 6) & 1;
    v2f aclo[4], achi[4];
    #pragma unroll
    for (int k = 0; k < 4; k++) { aclo[k] = (v2f){0.f,0.f}; achi[k] = (v2f){0.f,0.f}; }
    int nbeg = nh * 32;
    #pragma unroll 4
    for (int n = nbeg; n < nbeg + 32; n += 2) {
        u32 x0 = tile[(n * 16 + ((dp >> 2) ^ (n & 15))) * 4 + (dp & 3)];
        u32 x1 = tile[((n + 1) * 16 + ((dp >> 2) ^ ((n + 1) & 15))) * 4 + (dp & 3)];
        v2f alo = (v2f){bflo(x0), bflo(x1)};
        v2f ahi = (v2f){bfhi(x0), bfhi(x1)};
        #pragma unroll
        for (int k = 0; k < 4; k++) {
            int s = sA + 2 * k;
            if (s < 7) {
                v2f wp = *(const v2f*)&wt[s * 64 + n];   // ds_read_b64, broadcast
                aclo[k] = pkfma(alo, wp, aclo[k]);
                achi[k] = pkfma(ahi, wp, achi[k]);
            }
        }
    }
    // plain coalesced partial stores (no atomics)
    float* yp = ypart + (blk * 2 + nh) * 896;
    #pragma unroll
    for (int k = 0; k < 4; k++) {
        int s = sA + 2 * k;
        if (s < 7) {
            *(float2*)&yp[s * 128 + 2 * dp] =
                make_float2(aclo[k].x + aclo[k].y, achi[k].x + achi[k].y);
        }
    }
}

// ---------------- kernel 3: reduce + slot update, 512 thr, 4-way split-K ---
// q = t>>7 in 0..3 splits every matvec K-range; partials combined via LDS.
// Shorter dependent chains + 14 waves/CU (vs 7) attack the latency stall.
__global__ __launch_bounds__(512) void k_update(
    float* __restrict__ slots, const float* __restrict__ ypart,
    const float* __restrict__ Zp, const float* __restrict__ Ap,
    const float* __restrict__ g_in, const float* __restrict__ b_in,
    const u32* __restrict__ Pv, const u32* __restrict__ Pih,
    const u32* __restrict__ Phh, const float* __restrict__ b_ih,
    const float* __restrict__ b_hh, const float* __restrict__ g_m,
    const float* __restrict__ b_m, const u32* __restrict__ Pw1,
    const float* __restrict__ bb1, const u32* __restrict__ Pw2,
    const float* __restrict__ bb2, float* __restrict__ out,
    const float* __restrict__ g_s, const float* __restrict__ b_s,
    const float* __restrict__ WqT, const float* __restrict__ Wk,
    u16* __restrict__ Rg, float* __restrict__ c1ws, float* __restrict__ c2ws,
    int do_prep)
{
    __shared__ float ybuf[128], ub[128], hb[128], lb[128], t1b[256];
    __shared__ float red4w[4][128];     // generic 4-way combine
    __shared__ float g6[12][128];       // [q(4)][gate(3)] partials
    __shared__ float m1p[256];
    __shared__ float redA[2], redB[2];
    __shared__ float snb[128], qb[128], red4[4];
    __shared__ float Zsh, Ash;
    int bs = blockIdx.x, t = threadIdx.x;
    int b = bs / 7, s = bs - b * 7;
    int h = t & 127, q = t >> 7;        // q in 0..3
    // ---- A: reduce y partials (4-way over the 128 partial-slices) ----
    {
        float ysum = 0.f;
        const float* bp = ypart + ((size_t)(b * 128 + q * 32)) * 896 + s * 128 + h;
        #pragma unroll 8
        for (int c = 0; c < 32; c++) ysum += bp[(size_t)c * 896];
        red4w[q][h] = ysum;
    }
    // ---- Z/A partial reduce on waves 0 and 1 ----
    if (t < 64) {
        float z = Zp[((size_t)b * 64 + t) * 8 + s];
        for (int m = 32; m >= 1; m >>= 1) z += __shfl_xor(z, m);
        if (t == 0) Zsh = z;
    } else if (t < 128) {
        float a_ = Ap[((size_t)b * 64 + (t - 64)) * 8 + s];
        for (int m = 32; m >= 1; m >>= 1) a_ += __shfl_xor(a_, m);
        if (t == 64) Ash = a_;
    }
    __syncthreads();
    if (q == 0) {
        float ytot = red4w[0][h] + red4w[1][h] + red4w[2][h] + red4w[3][h];
        ybuf[h] = g_in[h] * (ytot - Ash) / Zsh + b_in[h];
        hb[h] = slots[bs * 128 + h];
    }
    __syncthreads();
    // ---- C: u = Wv @ y (64 dp-pairs, 16 per quad) ----
    {
        float a0 = 0.f;
        int dp0 = q * 16;
        #pragma unroll 4
        for (int dp = dp0; dp < dp0 + 16; dp++) {
            u32 w0 = Pv[dp * 128 + h];
            a0 += bflo(w0) * ybuf[2 * dp] + bfhi(w0) * ybuf[2 * dp + 1];
        }
        red4w[q][h] = a0;
    }
    __syncthreads();
    if (q == 0) ub[h] = red4w[0][h] + red4w[1][h] + red4w[2][h] + red4w[3][h];
    __syncthreads();
    // ---- D: GRU gates: q0,q1 -> gi(ub) K-halves; q2,q3 -> gh(hb) K-halves --
    {
        const u32* P = (q >= 2) ? Phh : Pih;
        const float* src = (q >= 2) ? hb : ub;
        int dp0 = (q & 1) * 32;
        float gv0 = 0.f, gv1 = 0.f, gv2 = 0.f;
        #pragma unroll 4
        for (int dp = dp0; dp < dp0 + 32; dp++) {
            float x0 = src[2 * dp], x1 = src[2 * dp + 1];
            u32 w0 = P[dp * 384 + h];
            u32 w1v = P[dp * 384 + 128 + h];
            u32 w2v = P[dp * 384 + 256 + h];
            gv0 += bflo(w0) * x0 + bfhi(w0) * x1;
            gv1 += bflo(w1v) * x0 + bfhi(w1v) * x1;
            gv2 += bflo(w2v) * x0 + bfhi(w2v) * x1;
        }
        g6[q * 3 + 0][h] = gv0; g6[q * 3 + 1][h] = gv1; g6[q * 3 + 2][h] = gv2;
    }
    __syncthreads();
    float hv = 0.f;
    if (q == 0) {
        float gi0 = g6[0][h] + g6[3][h] + b_ih[h];
        float gi1 = g6[1][h] + g6[4][h] + b_ih[128 + h];
        float gi2 = g6[2][h] + g6[5][h] + b_ih[256 + h];
        float gh0 = g6[6][h] + g6[9][h]  + b_hh[h];
        float gh1 = g6[7][h] + g6[10][h] + b_hh[128 + h];
        float gh2 = g6[8][h] + g6[11][h] + b_hh[256 + h];
        float rg = 1.0f / (1.0f + __expf(-(gi0 + gh0)));
        float zg = 1.0f / (1.0f + __expf(-(gi1 + gh1)));
        float ng = tanhf(gi2 + rg * gh2);
        hv = (1.0f - zg) * ng + zg * hb[h];
        float sm2 = hv, sq2 = hv * hv;
        for (int m = 32; m >= 1; m >>= 1) { sm2 += __shfl_xor(sm2, m); sq2 += __shfl_xor(sq2, m); }
        if ((t & 63) == 0) { redA[t >> 6] = sm2; redB[t >> 6] = sq2; }
    }
    __syncthreads();
    if (q == 0) {
        float sm2 = redA[0] + redA[1], sq2 = redB[0] + redB[1];
        float mean = sm2 * (1.0f / 128.0f);
        float var  = sq2 * (1.0f / 128.0f) - mean * mean;
        float rsq = rsqrtf(var + LN_EPS_);
        lb[h] = (hv - mean) * rsq * g_m[h] + b_m[h];
    }
    __syncthreads();
    // ---- F: mlp1: 256 outs, 2-way K split (o = t&255, kh = t>>8) ----
    {
        int o = t & 255, kh = t >> 8;
        float m1 = 0.f;
        int dp0 = kh * 32;
        #pragma unroll 4
        for (int dp = dp0; dp < dp0 + 32; dp++) {
            u32 w0 = Pw1[dp * 256 + o];
            m1 += bflo(w0) * lb[2 * dp] + bfhi(w0) * lb[2 * dp + 1];
        }
        if (kh) m1p[o] = m1;
        __syncthreads();
        if (!kh) t1b[o] = fmaxf(m1 + m1p[o] + bb1[o], 0.0f);
    }
    __syncthreads();
    // ---- G: mlp2: 128 outs, 4-way K split (128 mp-pairs, 32 per quad) ----
    {
        float o0 = 0.f;
        int mp0 = q * 32;
        #pragma unroll 4
        for (int mp = mp0; mp < mp0 + 32; mp++) {
            u32 w0 = Pw2[mp * 128 + h];
            o0 += bflo(w0) * t1b[2 * mp] + bfhi(w0) * t1b[2 * mp + 1];
        }
        red4w[q][h] = o0;
    }
    __syncthreads();
    float nv = 0.f;
    if (q == 0) {
        nv = hv + bb2[h] + red4w[0][h] + red4w[1][h] + red4w[2][h] + red4w[3][h];
        slots[bs * 128 + h] = nv;
        out[bs * 128 + h] = nv;
    }
    if (do_prep) {
        __syncthreads();
        // LN(slot) stats
        if (q == 0) {
            float smv = nv, sqv = nv * nv;
            for (int m = 32; m >= 1; m >>= 1) { smv += __shfl_xor(smv, m); sqv += __shfl_xor(sqv, m); }
            if ((t & 63) == 0) { red4[(t >> 6) * 2] = smv; red4[(t >> 6) * 2 + 1] = sqv; }
        }
        __syncthreads();
        float mean = (red4[0] + red4[2]) * (1.0f / 128.0f);
        float var  = (red4[1] + red4[3]) * (1.0f / 128.0f) - mean * mean;
        float rsv = rsqrtf(var + LN_EPS_);
        if (q == 0) snb[h] = (nv - mean) * rsv * g_s[h] + b_s[h];
        __syncthreads();
        // q[h] = sum_d WqT[d][h]*snb[d], 4-way (32 d per quad)
        {
            float qv = 0.f;
            int d0 = q * 32;
            #pragma unroll 4
            for (int d = d0; d < d0 + 32; d++) qv += WqT[d * 128 + h] * snb[d];
            red4w[q][h] = qv;
        }
        __syncthreads();
        if (q == 0) qb[h] = red4w[0][h] + red4w[1][h] + red4w[2][h] + red4w[3][h];
        __syncthreads();
        // r[h] = sum_j Wk[j][h]*qb[j], 4-way
        {
            float rv = 0.f;
            int j0 = q * 32;
            #pragma unroll 4
            for (int j = j0; j < j0 + 32; j++) rv += Wk[j * 128 + h] * qb[j];
            red4w[q][h] = rv;
        }
        __syncthreads();
        if (q == 0) {
            float r = (red4w[0][h] + red4w[1][h] + red4w[2][h] + red4w[3][h])
                      * 0.08838834764831845f;   // 128^-0.5
            float rt  = g_in[h] * r;
            float c2v = b_in[h] * r;
            Rg[((size_t)b * 16 + s) * 128 + h] = (u16)f2bf(rt);
            float c1p = rt, c2p = c2v;
            for (int m = 32; m >= 1; m >>= 1) { c1p += __shfl_xor(c1p, m); c2p += __shfl_xor(c2p, m); }
            if ((t & 63) == 0) { red4[(t >> 6) * 2] = c1p; red4[(t >> 6) * 2 + 1] = c2p; }
        }
        __syncthreads();
        if (t == 0) {
            c1ws[b * 8 + s] = red4[0] + red4[2];
            c2ws[b * 8 + s] = red4[1] + red4[3];
        }
    }
}

extern "C" void kernel_launch(void* const* d_in, const int* in_sizes, int n_in,
                              void* d_out, int out_size, void* d_ws, size_t ws_size,
                              hipStream_t stream) {
    const float* inputs     = (const float*)d_in[0];
    const float* slots_init = (const float*)d_in[1];
    const float* ln_in_g    = (const float*)d_in[2];
    const float* ln_in_b    = (const float*)d_in[3];
    const float* ln_s_g     = (const float*)d_in[4];
    const float* ln_s_b     = (const float*)d_in[5];
    const float* ln_m_g     = (const float*)d_in[6];
    const float* ln_m_b     = (const float*)d_in[7];
    const float* Wq         = (const float*)d_in[8];
    const float* Wk         = (const float*)d_in[9];
    const float* Wv         = (const float*)d_in[10];
    const float* W_ih       = (const float*)d_in[11];
    const float* W_hh       = (const float*)d_in[12];
    const float* b_ih       = (const float*)d_in[13];
    const float* b_hh       = (const float*)d_in[14];
    const float* mlp_w1     = (const float*)d_in[15];
    const float* mlp_b1     = (const float*)d_in[16];
    const float* mlp_w2     = (const float*)d_in[17];
    const float* mlp_b2     = (const float*)d_in[18];
    const float* slots_mu   = (const float*)d_in[19];
    const float* slots_ls   = (const float*)d_in[20];

    char* ws = (char*)d_ws;
    float* slots = (float*)(ws);                  // 229376
    u16*   Rg    = (u16*)  (ws + 229376);         // 262144 (bf16 R, 16 rows/b)
    float* c1ws  = (float*)(ws + 491520);         // 2048
    float* c2ws  = (float*)(ws + 493568);         // 2048
    float* WqT   = (float*)(ws + 495616);         // 65536
    u32*   Pv    = (u32*)  (ws + 561152);         // 32768
    u32*   Pih   = (u32*)  (ws + 593920);         // 98304
    u32*   Phh   = (u32*)  (ws + 692224);         // 98304
    u32*   Pw1   = (u32*)  (ws + 790528);         // 65536
    u32*   Pw2   = (u32*)  (ws + 856064);         // 65536
    float* Zp    = (float*)(ws + 921600);         // 131072
    float* Ap    = (float*)(ws + 1052672);        // 131072
    float* ypart = (float*)(ws + 1183744);        // 29360128
    u32*   Xbf   = (u32*)  (ws + 30543872);       // 67108864 (bf16 tile images)
    float* Sg    = (float*)(ws + 97652736);       // 2097152  -> total ~99.7 MB

    k_pack<<<560, 256, 0, stream>>>(Wq, Wv, W_ih, W_hh, mlp_w1, mlp_w2,
                                    WqT, Pv, Pih, Phh, Pw1, Pw2, (u32*)Rg);
    k_init_prep<<<448, 256, 0, stream>>>(slots_init, slots_mu, slots_ls, slots,
                                         ln_s_g, ln_s_b, WqT, Wk, ln_in_g, ln_in_b,
                                         Rg, c1ws, c2ws);
    for (int it = 0; it < 3; it++) {
        k_attn<<<dim3(64, 64), 256, 0, stream>>>(inputs, Rg, c1ws, c2ws,
                                                 ypart, Zp, Ap,
                                                 Xbf, Sg, (it == 0) ? 1 : 0);
        k_update<<<448, 512, 0, stream>>>(slots, ypart, Zp, Ap, ln_in_g, ln_in_b,
                                          Pv, Pih, Phh, b_ih, b_hh,
                                          ln_m_g, ln_m_b, Pw1, mlp_b1, Pw2, mlp_b2,
                                          (float*)d_out,
                                          ln_s_g, ln_s_b, WqT, Wk,
                                          Rg, c1ws, c2ws, (it < 2) ? 1 : 0);
    }
}

// Round 7
// 368.847 us; speedup vs baseline: 1.0916x; 1.0916x over previous
//
#include <hip/hip_runtime.h>
#include <hip/hip_bf16.h>
#include <stdint.h>

typedef unsigned int u32;
typedef unsigned short u16;
typedef float v2f __attribute__((ext_vector_type(2)));
typedef short bf16x8 __attribute__((ext_vector_type(8)));
typedef float f32x4 __attribute__((ext_vector_type(4)));

#define LN_EPS_ 1e-5f
#define EPS_ 1e-8f

__device__ __forceinline__ float bflo(u32 v){ return __uint_as_float(v << 16); }
__device__ __forceinline__ float bfhi(u32 v){ return __uint_as_float(v & 0xFFFF0000u); }
__device__ __forceinline__ u32 f2bf(float f){
    u32 x = __float_as_uint(f);
    return (x + 0x7FFFu + ((x >> 16) & 1u)) >> 16;
}
__device__ __forceinline__ u32 pack2bf(float a, float b){
    union { __hip_bfloat162 h; u32 u; } cv;
    cv.h = __float22bfloat162_rn(float2{a, b});
    return cv.u;
}
// packed fp32 math (gfx90a+/gfx950): 2 MACs per instruction
__device__ __forceinline__ v2f pkfma(v2f a, v2f b, v2f c){
    v2f d; asm("v_pk_fma_f32 %0, %1, %2, %3" : "=v"(d) : "v"(a), "v"(b), "v"(c)); return d;
}
__device__ __forceinline__ v2f pkadd(v2f a, v2f b){
    v2f d; asm("v_pk_add_f32 %0, %1, %2" : "=v"(d) : "v"(a), "v"(b)); return d;
}
__device__ __forceinline__ bf16x8 as_bf16x8(uint4 u){
    union { uint4 a; bf16x8 b; } c; c.a = u; return c.b;
}

// ---------------- kernel P: one-time weight prep ---------------------------
__global__ __launch_bounds__(256) void k_pack(
    const float* __restrict__ Wq, const float* __restrict__ Wv,
    const float* __restrict__ Wih, const float* __restrict__ Whh,
    const float* __restrict__ w1, const float* __restrict__ w2,
    float* __restrict__ WqT, u32* __restrict__ Pv, u32* __restrict__ Pih,
    u32* __restrict__ Phh, u32* __restrict__ Pw1, u32* __restrict__ Pw2,
    u32* __restrict__ Rg32)
{
    int i = blockIdx.x * 256 + threadIdx.x;
    if (i < 8192) {                                   // Pv
        int dp = i >> 7, o = i & 127;
        Pv[i] = pack2bf(Wv[o * 128 + 2 * dp], Wv[o * 128 + 2 * dp + 1]);
    } else if (i < 32768) {                           // Pih
        int r = i - 8192; int dp = r / 384, j = r - dp * 384;
        Pih[r] = pack2bf(Wih[j * 128 + 2 * dp], Wih[j * 128 + 2 * dp + 1]);
    } else if (i < 57344) {                           // Phh
        int r = i - 32768; int dp = r / 384, j = r - dp * 384;
        Phh[r] = pack2bf(Whh[j * 128 + 2 * dp], Whh[j * 128 + 2 * dp + 1]);
    } else if (i < 73728) {                           // Pw1
        int r = i - 57344; int dp = r >> 8, j = r & 255;
        Pw1[r] = pack2bf(w1[j * 128 + 2 * dp], w1[j * 128 + 2 * dp + 1]);
    } else if (i < 90112) {                           // Pw2
        int r = i - 73728; int mp = r >> 7, o = r & 127;
        Pw2[r] = pack2bf(w2[o * 256 + 2 * mp], w2[o * 256 + 2 * mp + 1]);
    } else if (i < 106496) {                          // WqT fp32
        int r = i - 90112; int d = r >> 7, o = r & 127;
        WqT[r] = Wq[o * 128 + d];
    } else if (i < 143360) {                          // zero Rg rows 7..15
        int r = i - 106496; int b = r / 576, rem = r - b * 576;
        Rg32[b * 1024 + 448 + rem] = 0;
    }
}

// ---------------- kernel 0: slots init + prep for iter 0 (256 thr) --------
__global__ __launch_bounds__(256) void k_init_prep(
    const float* __restrict__ slots_init, const float* __restrict__ mu,
    const float* __restrict__ ls, float* __restrict__ slots,
    const float* __restrict__ g_s, const float* __restrict__ b_s,
    const float* __restrict__ WqT, const float* __restrict__ Wk,
    const float* __restrict__ g_in, const float* __restrict__ b_in,
    u16* __restrict__ Rg, float* __restrict__ c1ws, float* __restrict__ c2ws)
{
    __shared__ float snb[128], qb[128], xch[128], red4[4];
    int bs = blockIdx.x, t = threadIdx.x;
    int b = bs / 7, s = bs - b * 7;
    int h = t & 127, half = t >> 7;
    float nv = 0.f;
    if (!half) {
        nv = mu[h] + expf(ls[h]) * slots_init[bs * 132 + h];
        slots[bs * 128 + h] = nv;
    }
    // LN stats
    if (!half) {
        float smv = nv, sqv = nv * nv;
        for (int m = 32; m >= 1; m >>= 1) { smv += __shfl_xor(smv, m); sqv += __shfl_xor(sqv, m); }
        if ((t & 63) == 0) { red4[(t >> 6) * 2] = smv; red4[(t >> 6) * 2 + 1] = sqv; }
    }
    __syncthreads();
    float mean = (red4[0] + red4[2]) * (1.0f / 128.0f);
    float var  = (red4[1] + red4[3]) * (1.0f / 128.0f) - mean * mean;
    float rsv = rsqrtf(var + LN_EPS_);
    if (!half) snb[h] = (nv - mean) * rsv * g_s[h] + b_s[h];
    __syncthreads();
    {
        float q0 = 0.f, q1 = 0.f;
        int d0 = half * 64;
        #pragma unroll 4
        for (int d = d0; d < d0 + 64; d += 2) {
            q0 += WqT[d * 128 + h] * snb[d];
            q1 += WqT[(d + 1) * 128 + h] * snb[d + 1];
        }
        if (half) xch[h] = q0 + q1;
        __syncthreads();
        if (!half) qb[h] = q0 + q1 + xch[h];
        __syncthreads();
    }
    float r0 = 0.f, r1 = 0.f;
    int j0 = half * 64;
    #pragma unroll 4
    for (int j = j0; j < j0 + 64; j += 2) {
        r0 += Wk[j * 128 + h] * qb[j];
        r1 += Wk[(j + 1) * 128 + h] * qb[j + 1];
    }
    if (half) xch[h] = r0 + r1;
    __syncthreads();
    if (!half) {
        float r = (r0 + r1 + xch[h]) * 0.08838834764831845f;   // 128^-0.5
        float rt  = g_in[h] * r;
        float c2v = b_in[h] * r;
        Rg[((size_t)b * 16 + s) * 128 + h] = (u16)f2bf(rt);
        float c1p = rt, c2p = c2v;
        for (int m = 32; m >= 1; m >>= 1) { c1p += __shfl_xor(c1p, m); c2p += __shfl_xor(c2p, m); }
        if ((t & 63) == 0) { red4[(t >> 6) * 2] = c1p; red4[(t >> 6) * 2 + 1] = c2p; }
    }
    __syncthreads();
    if (t == 0) {
        c1ws[b * 8 + s] = red4[0] + red4[2];
        c2ws[b * 8 + s] = red4[1] + red4[3];
    }
}

// ---------------- kernel 2: streaming attention (64-row tile, 8 blk/CU) ----
// r7: X-reuse reverted (r6 evidence: L3 already served cross-iteration X
// re-reads at 66 MB FETCH; materializing a bf16 image cost 67 MB write+RFO,
// it0 50->103 us). fp32 X read + pack + stats every iteration.
// ypart halved: nh halves combined in LDS (dead tile buffer) -> ONE 896-float
// partial per block (saves ~45 MB/iter of write+RFO+read traffic).
// phase1: MFMA 16x16x32_bf16, softmax in C-frag layout.
// phase2: n-paired pkfma -> LDS combine -> plain coalesced float2 stores.
__global__ __launch_bounds__(256, 8) void k_attn(
    const float* __restrict__ xin,
    const u16* __restrict__ Rg, const float* __restrict__ c1ws,
    const float* __restrict__ c2ws,
    float* __restrict__ ypart, float* __restrict__ Zp, float* __restrict__ Ap)
{
    __shared__ u32 tile[4096];          // 16 KB (reused as combine buffer)
    __shared__ __align__(16) float wt[448];   // w fp32 [s][n] (n local 0..63)
    __shared__ __align__(8)  float stats[128];// (mean, rs) per row
    __shared__ float c1l[16], c2l[16];
    __shared__ float redp[4][8], redw[4][8];
    int t = threadIdx.x;
    int b = blockIdx.y;
    int n0 = blockIdx.x * 64;
    int lane = t & 63, wv = t >> 6;
    int ls = lane & 15, lg = lane >> 4;
    size_t blk = (size_t)b * 64 + blockIdx.x;

    if (t < 16) {
        c1l[t] = (t < 7) ? c1ws[b * 8 + t] : 0.f;
        c2l[t] = (t < 7) ? c2ws[b * 8 + t] : 0.f;
    }

    // B-fragments (R) straight from global into VGPRs, reused all tiles
    bf16x8 bfr[4];
    {
        const u16* Rrow = Rg + ((size_t)b * 16 + ls) * 128;
        #pragma unroll
        for (int kk = 0; kk < 4; kk++)
            bfr[kk] = as_bf16x8(*(const uint4*)&Rrow[kk * 32 + lg * 8]);
    }

    // ---- pack + row stats from fp32 X ----
    {
        int r = t >> 2, p = t & 3;
        const float4* xg = (const float4*)(xin + ((size_t)b * 4096 + n0 + r) * 128 + p * 32);
        v2f smp = (v2f){0.f, 0.f}, sqp = (v2f){0.f, 0.f};
        #pragma unroll
        for (int i = 0; i < 8; i++) {
            float4 v = xg[i];
            v2f lo = (v2f){v.x, v.y}, hi = (v2f){v.z, v.w};
            smp = pkadd(smp, pkadd(lo, hi));
            sqp = pkfma(lo, lo, sqp);
            sqp = pkfma(hi, hi, sqp);
            int q = p * 4 + (i >> 1), rem = (i & 1) * 2;
            *(uint2*)&tile[(r * 16 + (q ^ (r & 15))) * 4 + rem] =
                make_uint2(pack2bf(v.x, v.y), pack2bf(v.z, v.w));
        }
        float sm = smp.x + smp.y, sq = sqp.x + sqp.y;
        sm += __shfl_xor(sm, 1); sq += __shfl_xor(sq, 1);
        sm += __shfl_xor(sm, 2); sq += __shfl_xor(sq, 2);
        if (!p) {
            float mean = sm * (1.0f / 128.0f);
            float var  = sq * (1.0f / 128.0f) - mean * mean;
            *(float2*)&stats[2 * r] = make_float2(mean, rsqrtf(var + LN_EPS_));
        }
    }
    __syncthreads();

    // ---- phase1: MFMA logits (one 16-row fragment per wave) ----
    f32x4 acc0 = {0.f, 0.f, 0.f, 0.f};
    {
        int m0 = wv * 16 + ls;
        #pragma unroll
        for (int kk = 0; kk < 4; kk++) {
            int q = kk * 4 + lg;
            bf16x8 a0 = as_bf16x8(*(const uint4*)&tile[(m0 * 16 + (q ^ ls)) * 4]);
            acc0 = __builtin_amdgcn_mfma_f32_16x16x32_bf16(a0, bfr[kk], acc0, 0, 0, 0);
        }
    }
    // ---- softmax epilogue in C-frag layout ----
    {
        float zsum = 0.f, asum = 0.f;
        float c1v = c1l[ls], c2v = c2l[ls];
        bool sv = ls < 7;
        int nbase = wv * 16 + lg * 4;
        #pragma unroll
        for (int r4 = 0; r4 < 4; r4++) {
            int n = nbase + r4;
            float2 stf = *(const float2*)&stats[2 * n];
            float L = sv ? (stf.y * (acc0[r4] - stf.x * c1v) + c2v) : -3.4e38f;
            float mx = L;
            mx = fmaxf(mx, __shfl_xor(mx, 1));
            mx = fmaxf(mx, __shfl_xor(mx, 2));
            mx = fmaxf(mx, __shfl_xor(mx, 4));
            mx = fmaxf(mx, __shfl_xor(mx, 8));
            float e = __expf(L - mx);
            float ssum = e;
            ssum += __shfl_xor(ssum, 1);
            ssum += __shfl_xor(ssum, 2);
            ssum += __shfl_xor(ssum, 4);
            ssum += __shfl_xor(ssum, 8);
            float p = e * (1.0f / ssum) + EPS_;
            float w = p * stf.y;
            if (sv) {
                wt[ls * 64 + n] = w;
                zsum += p;
                asum += w * stf.x;
            }
        }
        zsum += __shfl_xor(zsum, 16); zsum += __shfl_xor(zsum, 32);
        asum += __shfl_xor(asum, 16); asum += __shfl_xor(asum, 32);
        if (lane < 7) { redp[wv][lane] = zsum; redw[wv][lane] = asum; }
    }
    __syncthreads();
    if (t < 7)
        Zp[blk * 8 + t] = redp[0][t] + redp[1][t] + redp[2][t] + redp[3][t];
    else if (t >= 64 && t < 71) {
        int s = t - 64;
        Ap[blk * 8 + s] = redw[0][s] + redw[1][s] + redw[2][s] + redw[3][s];
    }

    // ---- phase2 ----
    int nh = t >> 7, dp = t & 63, sA = (t >> 6) & 1;
    v2f aclo[4], achi[4];
    #pragma unroll
    for (int k = 0; k < 4; k++) { aclo[k] = (v2f){0.f,0.f}; achi[k] = (v2f){0.f,0.f}; }
    int nbeg = nh * 32;
    #pragma unroll 4
    for (int n = nbeg; n < nbeg + 32; n += 2) {
        u32 x0 = tile[(n * 16 + ((dp >> 2) ^ (n & 15))) * 4 + (dp & 3)];
        u32 x1 = tile[((n + 1) * 16 + ((dp >> 2) ^ ((n + 1) & 15))) * 4 + (dp & 3)];
        v2f alo = (v2f){bflo(x0), bflo(x1)};
        v2f ahi = (v2f){bfhi(x0), bfhi(x1)};
        #pragma unroll
        for (int k = 0; k < 4; k++) {
            int s = sA + 2 * k;
            if (s < 7) {
                v2f wp = *(const v2f*)&wt[s * 64 + n];   // ds_read_b64, broadcast
                aclo[k] = pkfma(alo, wp, aclo[k]);
                achi[k] = pkfma(ahi, wp, achi[k]);
            }
        }
    }
    // ---- combine nh halves in LDS (tile is dead), single partial store ----
    float* ytmp = (float*)tile;
    __syncthreads();                    // all tile reads done
    if (nh) {
        #pragma unroll
        for (int k = 0; k < 4; k++) {
            int s = sA + 2 * k;
            if (s < 7)
                *(float2*)&ytmp[s * 128 + 2 * dp] =
                    make_float2(aclo[k].x + aclo[k].y, achi[k].x + achi[k].y);
        }
    }
    __syncthreads();
    if (!nh) {
        float* yp = ypart + blk * 896;
        #pragma unroll
        for (int k = 0; k < 4; k++) {
            int s = sA + 2 * k;
            if (s < 7) {
                float2 o = *(const float2*)&ytmp[s * 128 + 2 * dp];
                *(float2*)&yp[s * 128 + 2 * dp] =
                    make_float2(aclo[k].x + aclo[k].y + o.x,
                                achi[k].x + achi[k].y + o.y);
            }
        }
    }
}

// ---------------- kernel 3: reduce + slot update, 512 thr, 4-way split-K ---
// q = t>>7 in 0..3 splits every matvec K-range; partials combined via LDS.
__global__ __launch_bounds__(512) void k_update(
    float* __restrict__ slots, const float* __restrict__ ypart,
    const float* __restrict__ Zp, const float* __restrict__ Ap,
    const float* __restrict__ g_in, const float* __restrict__ b_in,
    const u32* __restrict__ Pv, const u32* __restrict__ Pih,
    const u32* __restrict__ Phh, const float* __restrict__ b_ih,
    const float* __restrict__ b_hh, const float* __restrict__ g_m,
    const float* __restrict__ b_m, const u32* __restrict__ Pw1,
    const float* __restrict__ bb1, const u32* __restrict__ Pw2,
    const float* __restrict__ bb2, float* __restrict__ out,
    const float* __restrict__ g_s, const float* __restrict__ b_s,
    const float* __restrict__ WqT, const float* __restrict__ Wk,
    u16* __restrict__ Rg, float* __restrict__ c1ws, float* __restrict__ c2ws,
    int do_prep)
{
    __shared__ float ybuf[128], ub[128], hb[128], lb[128], t1b[256];
    __shared__ float red4w[4][128];     // generic 4-way combine
    __shared__ float g6[12][128];       // [q(4)][gate(3)] partials
    __shared__ float m1p[256];
    __shared__ float redA[2], redB[2];
    __shared__ float snb[128], qb[128], red4[4];
    __shared__ float Zsh, Ash;
    int bs = blockIdx.x, t = threadIdx.x;
    int b = bs / 7, s = bs - b * 7;
    int h = t & 127, q = t >> 7;        // q in 0..3
    // ---- A: reduce y partials (64 block-partials, 16 per quad) ----
    {
        float ysum = 0.f;
        const float* bp = ypart + ((size_t)(b * 64 + q * 16)) * 896 + s * 128 + h;
        #pragma unroll 8
        for (int c = 0; c < 16; c++) ysum += bp[(size_t)c * 896];
        red4w[q][h] = ysum;
    }
    // ---- Z/A partial reduce on waves 0 and 1 ----
    if (t < 64) {
        float z = Zp[((size_t)b * 64 + t) * 8 + s];
        for (int m = 32; m >= 1; m >>= 1) z += __shfl_xor(z, m);
        if (t == 0) Zsh = z;
    } else if (t < 128) {
        float a_ = Ap[((size_t)b * 64 + (t - 64)) * 8 + s];
        for (int m = 32; m >= 1; m >>= 1) a_ += __shfl_xor(a_, m);
        if (t == 64) Ash = a_;
    }
    __syncthreads();
    if (q == 0) {
        float ytot = red4w[0][h] + red4w[1][h] + red4w[2][h] + red4w[3][h];
        ybuf[h] = g_in[h] * (ytot - Ash) / Zsh + b_in[h];
        hb[h] = slots[bs * 128 + h];
    }
    __syncthreads();
    // ---- C: u = Wv @ y (64 dp-pairs, 16 per quad) ----
    {
        float a0 = 0.f;
        int dp0 = q * 16;
        #pragma unroll 4
        for (int dp = dp0; dp < dp0 + 16; dp++) {
            u32 w0 = Pv[dp * 128 + h];
            a0 += bflo(w0) * ybuf[2 * dp] + bfhi(w0) * ybuf[2 * dp + 1];
        }
        red4w[q][h] = a0;
    }
    __syncthreads();
    if (q == 0) ub[h] = red4w[0][h] + red4w[1][h] + red4w[2][h] + red4w[3][h];
    __syncthreads();
    // ---- D: GRU gates: q0,q1 -> gi(ub) K-halves; q2,q3 -> gh(hb) K-halves --
    {
        const u32* P = (q >= 2) ? Phh : Pih;
        const float* src = (q >= 2) ? hb : ub;
        int dp0 = (q & 1) * 32;
        float gv0 = 0.f, gv1 = 0.f, gv2 = 0.f;
        #pragma unroll 4
        for (int dp = dp0; dp < dp0 + 32; dp++) {
            float x0 = src[2 * dp], x1 = src[2 * dp + 1];
            u32 w0 = P[dp * 384 + h];
            u32 w1v = P[dp * 384 + 128 + h];
            u32 w2v = P[dp * 384 + 256 + h];
            gv0 += bflo(w0) * x0 + bfhi(w0) * x1;
            gv1 += bflo(w1v) * x0 + bfhi(w1v) * x1;
            gv2 += bflo(w2v) * x0 + bfhi(w2v) * x1;
        }
        g6[q * 3 + 0][h] = gv0; g6[q * 3 + 1][h] = gv1; g6[q * 3 + 2][h] = gv2;
    }
    __syncthreads();
    float hv = 0.f;
    if (q == 0) {
        float gi0 = g6[0][h] + g6[3][h] + b_ih[h];
        float gi1 = g6[1][h] + g6[4][h] + b_ih[128 + h];
        float gi2 = g6[2][h] + g6[5][h] + b_ih[256 + h];
        float gh0 = g6[6][h] + g6[9][h]  + b_hh[h];
        float gh1 = g6[7][h] + g6[10][h] + b_hh[128 + h];
        float gh2 = g6[8][h] + g6[11][h] + b_hh[256 + h];
        float rg = 1.0f / (1.0f + __expf(-(gi0 + gh0)));
        float zg = 1.0f / (1.0f + __expf(-(gi1 + gh1)));
        float ng = tanhf(gi2 + rg * gh2);
        hv = (1.0f - zg) * ng + zg * hb[h];
        float sm2 = hv, sq2 = hv * hv;
        for (int m = 32; m >= 1; m >>= 1) { sm2 += __shfl_xor(sm2, m); sq2 += __shfl_xor(sq2, m); }
        if ((t & 63) == 0) { redA[t >> 6] = sm2; redB[t >> 6] = sq2; }
    }
    __syncthreads();
    if (q == 0) {
        float sm2 = redA[0] + redA[1], sq2 = redB[0] + redB[1];
        float mean = sm2 * (1.0f / 128.0f);
        float var  = sq2 * (1.0f / 128.0f) - mean * mean;
        float rsq = rsqrtf(var + LN_EPS_);
        lb[h] = (hv - mean) * rsq * g_m[h] + b_m[h];
    }
    __syncthreads();
    // ---- F: mlp1: 256 outs, 2-way K split (o = t&255, kh = t>>8) ----
    {
        int o = t & 255, kh = t >> 8;
        float m1 = 0.f;
        int dp0 = kh * 32;
        #pragma unroll 4
        for (int dp = dp0; dp < dp0 + 32; dp++) {
            u32 w0 = Pw1[dp * 256 + o];
            m1 += bflo(w0) * lb[2 * dp] + bfhi(w0) * lb[2 * dp + 1];
        }
        if (kh) m1p[o] = m1;
        __syncthreads();
        if (!kh) t1b[o] = fmaxf(m1 + m1p[o] + bb1[o], 0.0f);
    }
    __syncthreads();
    // ---- G: mlp2: 128 outs, 4-way K split (128 mp-pairs, 32 per quad) ----
    {
        float o0 = 0.f;
        int mp0 = q * 32;
        #pragma unroll 4
        for (int mp = mp0; mp < mp0 + 32; mp++) {
            u32 w0 = Pw2[mp * 128 + h];
            o0 += bflo(w0) * t1b[2 * mp] + bfhi(w0) * t1b[2 * mp + 1];
        }
        red4w[q][h] = o0;
    }
    __syncthreads();
    float nv = 0.f;
    if (q == 0) {
        nv = hv + bb2[h] + red4w[0][h] + red4w[1][h] + red4w[2][h] + red4w[3][h];
        slots[bs * 128 + h] = nv;
        out[bs * 128 + h] = nv;
    }
    if (do_prep) {
        __syncthreads();
        // LN(slot) stats
        if (q == 0) {
            float smv = nv, sqv = nv * nv;
            for (int m = 32; m >= 1; m >>= 1) { smv += __shfl_xor(smv, m); sqv += __shfl_xor(sqv, m); }
            if ((t & 63) == 0) { red4[(t >> 6) * 2] = smv; red4[(t >> 6) * 2 + 1] = sqv; }
        }
        __syncthreads();
        float mean = (red4[0] + red4[2]) * (1.0f / 128.0f);
        float var  = (red4[1] + red4[3]) * (1.0f / 128.0f) - mean * mean;
        float rsv = rsqrtf(var + LN_EPS_);
        if (q == 0) snb[h] = (nv - mean) * rsv * g_s[h] + b_s[h];
        __syncthreads();
        // q[h] = sum_d WqT[d][h]*snb[d], 4-way (32 d per quad)
        {
            float qv = 0.f;
            int d0 = q * 32;
            #pragma unroll 4
            for (int d = d0; d < d0 + 32; d++) qv += WqT[d * 128 + h] * snb[d];
            red4w[q][h] = qv;
        }
        __syncthreads();
        if (q == 0) qb[h] = red4w[0][h] + red4w[1][h] + red4w[2][h] + red4w[3][h];
        __syncthreads();
        // r[h] = sum_j Wk[j][h]*qb[j], 4-way
        {
            float rv = 0.f;
            int j0 = q * 32;
            #pragma unroll 4
            for (int j = j0; j < j0 + 32; j++) rv += Wk[j * 128 + h] * qb[j];
            red4w[q][h] = rv;
        }
        __syncthreads();
        if (q == 0) {
            float r = (red4w[0][h] + red4w[1][h] + red4w[2][h] + red4w[3][h])
                      * 0.08838834764831845f;   // 128^-0.5
            float rt  = g_in[h] * r;
            float c2v = b_in[h] * r;
            Rg[((size_t)b * 16 + s) * 128 + h] = (u16)f2bf(rt);
            float c1p = rt, c2p = c2v;
            for (int m = 32; m >= 1; m >>= 1) { c1p += __shfl_xor(c1p, m); c2p += __shfl_xor(c2p, m); }
            if ((t & 63) == 0) { red4[(t >> 6) * 2] = c1p; red4[(t >> 6) * 2 + 1] = c2p; }
        }
        __syncthreads();
        if (t == 0) {
            c1ws[b * 8 + s] = red4[0] + red4[2];
            c2ws[b * 8 + s] = red4[1] + red4[3];
        }
    }
}

extern "C" void kernel_launch(void* const* d_in, const int* in_sizes, int n_in,
                              void* d_out, int out_size, void* d_ws, size_t ws_size,
                              hipStream_t stream) {
    const float* inputs     = (const float*)d_in[0];
    const float* slots_init = (const float*)d_in[1];
    const float* ln_in_g    = (const float*)d_in[2];
    const float* ln_in_b    = (const float*)d_in[3];
    const float* ln_s_g     = (const float*)d_in[4];
    const float* ln_s_b     = (const float*)d_in[5];
    const float* ln_m_g     = (const float*)d_in[6];
    const float* ln_m_b     = (const float*)d_in[7];
    const float* Wq         = (const float*)d_in[8];
    const float* Wk         = (const float*)d_in[9];
    const float* Wv         = (const float*)d_in[10];
    const float* W_ih       = (const float*)d_in[11];
    const float* W_hh       = (const float*)d_in[12];
    const float* b_ih       = (const float*)d_in[13];
    const float* b_hh       = (const float*)d_in[14];
    const float* mlp_w1     = (const float*)d_in[15];
    const float* mlp_b1     = (const float*)d_in[16];
    const float* mlp_w2     = (const float*)d_in[17];
    const float* mlp_b2     = (const float*)d_in[18];
    const float* slots_mu   = (const float*)d_in[19];
    const float* slots_ls   = (const float*)d_in[20];

    char* ws = (char*)d_ws;
    float* slots = (float*)(ws);                  // 229376
    u16*   Rg    = (u16*)  (ws + 229376);         // 262144 (bf16 R, 16 rows/b)
    float* c1ws  = (float*)(ws + 491520);         // 2048
    float* c2ws  = (float*)(ws + 493568);         // 2048
    float* WqT   = (float*)(ws + 495616);         // 65536
    u32*   Pv    = (u32*)  (ws + 561152);         // 32768
    u32*   Pih   = (u32*)  (ws + 593920);         // 98304
    u32*   Phh   = (u32*)  (ws + 692224);         // 98304
    u32*   Pw1   = (u32*)  (ws + 790528);         // 65536
    u32*   Pw2   = (u32*)  (ws + 856064);         // 65536
    float* Zp    = (float*)(ws + 921600);         // 131072
    float* Ap    = (float*)(ws + 1052672);        // 131072
    float* ypart = (float*)(ws + 1183744);        // 14680064 -> total ~15.9 MB

    k_pack<<<560, 256, 0, stream>>>(Wq, Wv, W_ih, W_hh, mlp_w1, mlp_w2,
                                    WqT, Pv, Pih, Phh, Pw1, Pw2, (u32*)Rg);
    k_init_prep<<<448, 256, 0, stream>>>(slots_init, slots_mu, slots_ls, slots,
                                         ln_s_g, ln_s_b, WqT, Wk, ln_in_g, ln_in_b,
                                         Rg, c1ws, c2ws);
    for (int it = 0; it < 3; it++) {
        k_attn<<<dim3(64, 64), 256, 0, stream>>>(inputs, Rg, c1ws, c2ws,
                                                 ypart, Zp, Ap);
        k_update<<<448, 512, 0, stream>>>(slots, ypart, Zp, Ap, ln_in_g, ln_in_b,
                                          Pv, Pih, Phh, b_ih, b_hh,
                                          ln_m_g, ln_m_b, Pw1, mlp_b1, Pw2, mlp_b2,
                                          (float*)d_out,
                                          ln_s_g, ln_s_b, WqT, Wk,
                                          Rg, c1ws, c2ws, (it < 2) ? 1 : 0);
    }
}

// Round 8
// 363.118 us; speedup vs baseline: 1.1088x; 1.0158x over previous
//
#include <hip/hip_runtime.h>
#include <hip/hip_bf16.h>
#include <stdint.h>

typedef unsigned int u32;
typedef unsigned short u16;
typedef float v2f __attribute__((ext_vector_type(2)));
typedef short bf16x8 __attribute__((ext_vector_type(8)));
typedef float f32x4 __attribute__((ext_vector_type(4)));

#define LN_EPS_ 1e-5f
#define EPS_ 1e-8f

__device__ __forceinline__ float bflo(u32 v){ return __uint_as_float(v << 16); }
__device__ __forceinline__ float bfhi(u32 v){ return __uint_as_float(v & 0xFFFF0000u); }
__device__ __forceinline__ u32 f2bf(float f){
    u32 x = __float_as_uint(f);
    return (x + 0x7FFFu + ((x >> 16) & 1u)) >> 16;
}
__device__ __forceinline__ u32 pack2bf(float a, float b){
    union { __hip_bfloat162 h; u32 u; } cv;
    cv.h = __float22bfloat162_rn(float2{a, b});
    return cv.u;
}
// packed fp32 math (gfx90a+/gfx950): 2 MACs per instruction
__device__ __forceinline__ v2f pkfma(v2f a, v2f b, v2f c){
    v2f d; asm("v_pk_fma_f32 %0, %1, %2, %3" : "=v"(d) : "v"(a), "v"(b), "v"(c)); return d;
}
__device__ __forceinline__ v2f pkadd(v2f a, v2f b){
    v2f d; asm("v_pk_add_f32 %0, %1, %2" : "=v"(d) : "v"(a), "v"(b)); return d;
}
__device__ __forceinline__ bf16x8 as_bf16x8(uint4 u){
    union { uint4 a; bf16x8 b; } c; c.a = u; return c.b;
}

// ---------------- kernel P: one-time weight prep ---------------------------
__global__ __launch_bounds__(256) void k_pack(
    const float* __restrict__ Wq, const float* __restrict__ Wv,
    const float* __restrict__ Wih, const float* __restrict__ Whh,
    const float* __restrict__ w1, const float* __restrict__ w2,
    float* __restrict__ WqT, u32* __restrict__ Pv, u32* __restrict__ Pih,
    u32* __restrict__ Phh, u32* __restrict__ Pw1, u32* __restrict__ Pw2,
    u32* __restrict__ Rg32)
{
    int i = blockIdx.x * 256 + threadIdx.x;
    if (i < 8192) {                                   // Pv
        int dp = i >> 7, o = i & 127;
        Pv[i] = pack2bf(Wv[o * 128 + 2 * dp], Wv[o * 128 + 2 * dp + 1]);
    } else if (i < 32768) {                           // Pih
        int r = i - 8192; int dp = r / 384, j = r - dp * 384;
        Pih[r] = pack2bf(Wih[j * 128 + 2 * dp], Wih[j * 128 + 2 * dp + 1]);
    } else if (i < 57344) {                           // Phh
        int r = i - 32768; int dp = r / 384, j = r - dp * 384;
        Phh[r] = pack2bf(Whh[j * 128 + 2 * dp], Whh[j * 128 + 2 * dp + 1]);
    } else if (i < 73728) {                           // Pw1
        int r = i - 57344; int dp = r >> 8, j = r & 255;
        Pw1[r] = pack2bf(w1[j * 128 + 2 * dp], w1[j * 128 + 2 * dp + 1]);
    } else if (i < 90112) {                           // Pw2
        int r = i - 73728; int mp = r >> 7, o = r & 127;
        Pw2[r] = pack2bf(w2[o * 256 + 2 * mp], w2[o * 256 + 2 * mp + 1]);
    } else if (i < 106496) {                          // WqT fp32
        int r = i - 90112; int d = r >> 7, o = r & 127;
        WqT[r] = Wq[o * 128 + d];
    } else if (i < 143360) {                          // zero Rg rows 7..15
        int r = i - 106496; int b = r / 576, rem = r - b * 576;
        Rg32[b * 1024 + 448 + rem] = 0;
    }
}

// ---------------- kernel 0: slots init + prep for iter 0 (256 thr) --------
__global__ __launch_bounds__(256) void k_init_prep(
    const float* __restrict__ slots_init, const float* __restrict__ mu,
    const float* __restrict__ ls, float* __restrict__ slots,
    const float* __restrict__ g_s, const float* __restrict__ b_s,
    const float* __restrict__ WqT, const float* __restrict__ Wk,
    const float* __restrict__ g_in, const float* __restrict__ b_in,
    u16* __restrict__ Rg, float* __restrict__ c1ws, float* __restrict__ c2ws)
{
    __shared__ float snb[128], qb[128], xch[128], red4[4];
    int bs = blockIdx.x, t = threadIdx.x;
    int b = bs / 7, s = bs - b * 7;
    int h = t & 127, half = t >> 7;
    float nv = 0.f;
    if (!half) {
        nv = mu[h] + expf(ls[h]) * slots_init[bs * 132 + h];
        slots[bs * 128 + h] = nv;
    }
    // LN stats
    if (!half) {
        float smv = nv, sqv = nv * nv;
        for (int m = 32; m >= 1; m >>= 1) { smv += __shfl_xor(smv, m); sqv += __shfl_xor(sqv, m); }
        if ((t & 63) == 0) { red4[(t >> 6) * 2] = smv; red4[(t >> 6) * 2 + 1] = sqv; }
    }
    __syncthreads();
    float mean = (red4[0] + red4[2]) * (1.0f / 128.0f);
    float var  = (red4[1] + red4[3]) * (1.0f / 128.0f) - mean * mean;
    float rsv = rsqrtf(var + LN_EPS_);
    if (!half) snb[h] = (nv - mean) * rsv * g_s[h] + b_s[h];
    __syncthreads();
    {
        float q0 = 0.f, q1 = 0.f;
        int d0 = half * 64;
        #pragma unroll 4
        for (int d = d0; d < d0 + 64; d += 2) {
            q0 += WqT[d * 128 + h] * snb[d];
            q1 += WqT[(d + 1) * 128 + h] * snb[d + 1];
        }
        if (half) xch[h] = q0 + q1;
        __syncthreads();
        if (!half) qb[h] = q0 + q1 + xch[h];
        __syncthreads();
    }
    float r0 = 0.f, r1 = 0.f;
    int j0 = half * 64;
    #pragma unroll 4
    for (int j = j0; j < j0 + 64; j += 2) {
        r0 += Wk[j * 128 + h] * qb[j];
        r1 += Wk[(j + 1) * 128 + h] * qb[j + 1];
    }
    if (half) xch[h] = r0 + r1;
    __syncthreads();
    if (!half) {
        float r = (r0 + r1 + xch[h]) * 0.08838834764831845f;   // 128^-0.5
        float rt  = g_in[h] * r;
        float c2v = b_in[h] * r;
        Rg[((size_t)b * 16 + s) * 128 + h] = (u16)f2bf(rt);
        float c1p = rt, c2p = c2v;
        for (int m = 32; m >= 1; m >>= 1) { c1p += __shfl_xor(c1p, m); c2p += __shfl_xor(c2p, m); }
        if ((t & 63) == 0) { red4[(t >> 6) * 2] = c1p; red4[(t >> 6) * 2 + 1] = c2p; }
    }
    __syncthreads();
    if (t == 0) {
        c1ws[b * 8 + s] = red4[0] + red4[2];
        c2ws[b * 8 + s] = red4[1] + red4[3];
    }
}

// ---------------- kernel 2: streaming attention (64-row tile, 8 blk/CU) ----
// r8: phase2 ported to MFMA. y[s][h] = sum_n w[s][n] X[n][h] is a
// 16(s)x128(h)x64(n) GEMM per block: A = w (bf16, packed into wtp[16][36]
// u32, stride-36 pad -> 2-way-free b128 reads), B = X gathered from the
// swizzled tile (8 scalar u32 reads + in-reg pack per frag), C-frag stored
// straight to ypart (lane holds y[s=lg*4+r][h=hsub*16+ls]).
// Replaces ~96 LDS + ~200 VALU per thread with ~34 LDS + ~70 VALU + 4 MFMA.
__global__ __launch_bounds__(256, 8) void k_attn(
    const float* __restrict__ xin,
    const u16* __restrict__ Rg, const float* __restrict__ c1ws,
    const float* __restrict__ c2ws,
    float* __restrict__ ypart, float* __restrict__ Zp, float* __restrict__ Ap)
{
    __shared__ u32 tile[4096];          // 16 KB
    __shared__ u32 wtp[16 * 36];        // w bf16-pairs [s][np], stride-36 pad
    __shared__ __align__(8) float stats[128]; // (mean, rs) per row
    __shared__ float c1l[16], c2l[16];
    __shared__ float redp[4][8], redw[4][8];
    int t = threadIdx.x;
    int b = blockIdx.y;
    int n0 = blockIdx.x * 64;
    int lane = t & 63, wv = t >> 6;
    int ls = lane & 15, lg = lane >> 4;
    size_t blk = (size_t)b * 64 + blockIdx.x;

    if (t < 16) {
        c1l[t] = (t < 7) ? c1ws[b * 8 + t] : 0.f;
        c2l[t] = (t < 7) ? c2ws[b * 8 + t] : 0.f;
    }

    // B-fragments (R) straight from global into VGPRs, reused all tiles
    bf16x8 bfr[4];
    {
        const u16* Rrow = Rg + ((size_t)b * 16 + ls) * 128;
        #pragma unroll
        for (int kk = 0; kk < 4; kk++)
            bfr[kk] = as_bf16x8(*(const uint4*)&Rrow[kk * 32 + lg * 8]);
    }

    // ---- pack + row stats from fp32 X ----
    {
        int r = t >> 2, p = t & 3;
        const float4* xg = (const float4*)(xin + ((size_t)b * 4096 + n0 + r) * 128 + p * 32);
        v2f smp = (v2f){0.f, 0.f}, sqp = (v2f){0.f, 0.f};
        #pragma unroll
        for (int i = 0; i < 8; i++) {
            float4 v = xg[i];
            v2f lo = (v2f){v.x, v.y}, hi = (v2f){v.z, v.w};
            smp = pkadd(smp, pkadd(lo, hi));
            sqp = pkfma(lo, lo, sqp);
            sqp = pkfma(hi, hi, sqp);
            int q = p * 4 + (i >> 1), rem = (i & 1) * 2;
            *(uint2*)&tile[(r * 16 + (q ^ (r & 15))) * 4 + rem] =
                make_uint2(pack2bf(v.x, v.y), pack2bf(v.z, v.w));
        }
        float sm = smp.x + smp.y, sq = sqp.x + sqp.y;
        sm += __shfl_xor(sm, 1); sq += __shfl_xor(sq, 1);
        sm += __shfl_xor(sm, 2); sq += __shfl_xor(sq, 2);
        if (!p) {
            float mean = sm * (1.0f / 128.0f);
            float var  = sq * (1.0f / 128.0f) - mean * mean;
            *(float2*)&stats[2 * r] = make_float2(mean, rsqrtf(var + LN_EPS_));
        }
    }
    __syncthreads();

    // ---- phase1: MFMA logits (one 16-row fragment per wave) ----
    f32x4 acc0 = {0.f, 0.f, 0.f, 0.f};
    {
        int m0 = wv * 16 + ls;
        #pragma unroll
        for (int kk = 0; kk < 4; kk++) {
            int q = kk * 4 + lg;
            bf16x8 a0 = as_bf16x8(*(const uint4*)&tile[(m0 * 16 + (q ^ ls)) * 4]);
            acc0 = __builtin_amdgcn_mfma_f32_16x16x32_bf16(a0, bfr[kk], acc0, 0, 0, 0);
        }
    }
    // ---- softmax epilogue in C-frag layout; w packed bf16 into wtp ----
    {
        float zsum = 0.f, asum = 0.f;
        float c1v = c1l[ls], c2v = c2l[ls];
        bool sv = ls < 7;
        int nbase = wv * 16 + lg * 4;
        float wv4[4];
        #pragma unroll
        for (int r4 = 0; r4 < 4; r4++) {
            int n = nbase + r4;
            float2 stf = *(const float2*)&stats[2 * n];
            float L = sv ? (stf.y * (acc0[r4] - stf.x * c1v) + c2v) : -3.4e38f;
            float mx = L;
            mx = fmaxf(mx, __shfl_xor(mx, 1));
            mx = fmaxf(mx, __shfl_xor(mx, 2));
            mx = fmaxf(mx, __shfl_xor(mx, 4));
            mx = fmaxf(mx, __shfl_xor(mx, 8));
            float e = __expf(L - mx);
            float ssum = e;
            ssum += __shfl_xor(ssum, 1);
            ssum += __shfl_xor(ssum, 2);
            ssum += __shfl_xor(ssum, 4);
            ssum += __shfl_xor(ssum, 8);
            float p = e * (1.0f / ssum) + EPS_;
            float w = p * stf.y;
            wv4[r4] = w;
            if (sv) {
                zsum += p;
                asum += w * stf.x;
            }
        }
        // pack 4 w's (2 u32) into wtp row ls; rows 7..15 get tiny junk (unused)
        wtp[ls * 36 + wv * 8 + lg * 2 + 0] = pack2bf(wv4[0], wv4[1]);
        wtp[ls * 36 + wv * 8 + lg * 2 + 1] = pack2bf(wv4[2], wv4[3]);
        zsum += __shfl_xor(zsum, 16); zsum += __shfl_xor(zsum, 32);
        asum += __shfl_xor(asum, 16); asum += __shfl_xor(asum, 32);
        if (lane < 7) { redp[wv][lane] = zsum; redw[wv][lane] = asum; }
    }
    __syncthreads();
    if (t < 7)
        Zp[blk * 8 + t] = redp[0][t] + redp[1][t] + redp[2][t] + redp[3][t];
    else if (t >= 64 && t < 71) {
        int s = t - 64;
        Ap[blk * 8 + s] = redw[0][s] + redw[1][s] + redw[2][s] + redw[3][s];
    }

    // ---- phase2: MFMA y-partials ----
    // A-frags: w rows (shared across h-subtiles), one per K-step
    bf16x8 af0 = as_bf16x8(*(const uint4*)&wtp[ls * 36 + lg * 4]);
    bf16x8 af1 = as_bf16x8(*(const uint4*)&wtp[ls * 36 + 16 + lg * 4]);
    float* yp = ypart + blk * 896;
    u32 selhi = ls & 1;
    #pragma unroll
    for (int hs = 0; hs < 2; hs++) {
        int hsub = wv * 2 + hs;
        int dp = hsub * 8 + (ls >> 1);
        int qc = dp >> 2, rem = dp & 3;
        f32x4 acc2 = {0.f, 0.f, 0.f, 0.f};
        #pragma unroll
        for (int ks = 0; ks < 2; ks++) {
            u32 xr[8];
            #pragma unroll
            for (int i = 0; i < 8; i++) {
                int n = ks * 32 + lg * 8 + i;
                xr[i] = tile[(n * 16 + (qc ^ (n & 15))) * 4 + rem];
            }
            u32 bw[4];
            #pragma unroll
            for (int j = 0; j < 4; j++) {
                u32 a = xr[2 * j], c = xr[2 * j + 1];
                u32 lo16 = selhi ? (a >> 16) : (a & 0xFFFFu);
                u32 hi16 = selhi ? (c & 0xFFFF0000u) : (c << 16);
                bw[j] = lo16 | hi16;
            }
            acc2 = __builtin_amdgcn_mfma_f32_16x16x32_bf16(
                ks ? af1 : af0,
                as_bf16x8(make_uint4(bw[0], bw[1], bw[2], bw[3])),
                acc2, 0, 0, 0);
        }
        int h = hsub * 16 + ls;
        #pragma unroll
        for (int r = 0; r < 4; r++) {
            int s = lg * 4 + r;
            if (s < 7) yp[s * 128 + h] = acc2[r];
        }
    }
}

// ---------------- kernel 3: reduce + slot update, 512 thr, 4-way split-K ---
// q = t>>7 in 0..3 splits every matvec K-range; partials combined via LDS.
__global__ __launch_bounds__(512) void k_update(
    float* __restrict__ slots, const float* __restrict__ ypart,
    const float* __restrict__ Zp, const float* __restrict__ Ap,
    const float* __restrict__ g_in, const float* __restrict__ b_in,
    const u32* __restrict__ Pv, const u32* __restrict__ Pih,
    const u32* __restrict__ Phh, const float* __restrict__ b_ih,
    const float* __restrict__ b_hh, const float* __restrict__ g_m,
    const float* __restrict__ b_m, const u32* __restrict__ Pw1,
    const float* __restrict__ bb1, const u32* __restrict__ Pw2,
    const float* __restrict__ bb2, float* __restrict__ out,
    const float* __restrict__ g_s, const float* __restrict__ b_s,
    const float* __restrict__ WqT, const float* __restrict__ Wk,
    u16* __restrict__ Rg, float* __restrict__ c1ws, float* __restrict__ c2ws,
    int do_prep)
{
    __shared__ float ybuf[128], ub[128], hb[128], lb[128], t1b[256];
    __shared__ float red4w[4][128];     // generic 4-way combine
    __shared__ float g6[12][128];       // [q(4)][gate(3)] partials
    __shared__ float m1p[256];
    __shared__ float redA[2], redB[2];
    __shared__ float snb[128], qb[128], red4[4];
    __shared__ float Zsh, Ash;
    int bs = blockIdx.x, t = threadIdx.x;
    int b = bs / 7, s = bs - b * 7;
    int h = t & 127, q = t >> 7;        // q in 0..3
    // ---- A: reduce y partials (64 block-partials, 16 per quad) ----
    {
        float ysum = 0.f;
        const float* bp = ypart + ((size_t)(b * 64 + q * 16)) * 896 + s * 128 + h;
        #pragma unroll 8
        for (int c = 0; c < 16; c++) ysum += bp[(size_t)c * 896];
        red4w[q][h] = ysum;
    }
    // ---- Z/A partial reduce on waves 0 and 1 ----
    if (t < 64) {
        float z = Zp[((size_t)b * 64 + t) * 8 + s];
        for (int m = 32; m >= 1; m >>= 1) z += __shfl_xor(z, m);
        if (t == 0) Zsh = z;
    } else if (t < 128) {
        float a_ = Ap[((size_t)b * 64 + (t - 64)) * 8 + s];
        for (int m = 32; m >= 1; m >>= 1) a_ += __shfl_xor(a_, m);
        if (t == 64) Ash = a_;
    }
    __syncthreads();
    if (q == 0) {
        float ytot = red4w[0][h] + red4w[1][h] + red4w[2][h] + red4w[3][h];
        ybuf[h] = g_in[h] * (ytot - Ash) / Zsh + b_in[h];
        hb[h] = slots[bs * 128 + h];
    }
    __syncthreads();
    // ---- C: u = Wv @ y (64 dp-pairs, 16 per quad) ----
    {
        float a0 = 0.f;
        int dp0 = q * 16;
        #pragma unroll 4
        for (int dp = dp0; dp < dp0 + 16; dp++) {
            u32 w0 = Pv[dp * 128 + h];
            a0 += bflo(w0) * ybuf[2 * dp] + bfhi(w0) * ybuf[2 * dp + 1];
        }
        red4w[q][h] = a0;
    }
    __syncthreads();
    if (q == 0) ub[h] = red4w[0][h] + red4w[1][h] + red4w[2][h] + red4w[3][h];
    __syncthreads();
    // ---- D: GRU gates: q0,q1 -> gi(ub) K-halves; q2,q3 -> gh(hb) K-halves --
    {
        const u32* P = (q >= 2) ? Phh : Pih;
        const float* src = (q >= 2) ? hb : ub;
        int dp0 = (q & 1) * 32;
        float gv0 = 0.f, gv1 = 0.f, gv2 = 0.f;
        #pragma unroll 4
        for (int dp = dp0; dp < dp0 + 32; dp++) {
            float x0 = src[2 * dp], x1 = src[2 * dp + 1];
            u32 w0 = P[dp * 384 + h];
            u32 w1v = P[dp * 384 + 128 + h];
            u32 w2v = P[dp * 384 + 256 + h];
            gv0 += bflo(w0) * x0 + bfhi(w0) * x1;
            gv1 += bflo(w1v) * x0 + bfhi(w1v) * x1;
            gv2 += bflo(w2v) * x0 + bfhi(w2v) * x1;
        }
        g6[q * 3 + 0][h] = gv0; g6[q * 3 + 1][h] = gv1; g6[q * 3 + 2][h] = gv2;
    }
    __syncthreads();
    float hv = 0.f;
    if (q == 0) {
        float gi0 = g6[0][h] + g6[3][h] + b_ih[h];
        float gi1 = g6[1][h] + g6[4][h] + b_ih[128 + h];
        float gi2 = g6[2][h] + g6[5][h] + b_ih[256 + h];
        float gh0 = g6[6][h] + g6[9][h]  + b_hh[h];
        float gh1 = g6[7][h] + g6[10][h] + b_hh[128 + h];
        float gh2 = g6[8][h] + g6[11][h] + b_hh[256 + h];
        float rg = 1.0f / (1.0f + __expf(-(gi0 + gh0)));
        float zg = 1.0f / (1.0f + __expf(-(gi1 + gh1)));
        float ng = tanhf(gi2 + rg * gh2);
        hv = (1.0f - zg) * ng + zg * hb[h];
        float sm2 = hv, sq2 = hv * hv;
        for (int m = 32; m >= 1; m >>= 1) { sm2 += __shfl_xor(sm2, m); sq2 += __shfl_xor(sq2, m); }
        if ((t & 63) == 0) { redA[t >> 6] = sm2; redB[t >> 6] = sq2; }
    }
    __syncthreads();
    if (q == 0) {
        float sm2 = redA[0] + redA[1], sq2 = redB[0] + redB[1];
        float mean = sm2 * (1.0f / 128.0f);
        float var  = sq2 * (1.0f / 128.0f) - mean * mean;
        float rsq = rsqrtf(var + LN_EPS_);
        lb[h] = (hv - mean) * rsq * g_m[h] + b_m[h];
    }
    __syncthreads();
    // ---- F: mlp1: 256 outs, 2-way K split (o = t&255, kh = t>>8) ----
    {
        int o = t & 255, kh = t >> 8;
        float m1 = 0.f;
        int dp0 = kh * 32;
        #pragma unroll 4
        for (int dp = dp0; dp < dp0 + 32; dp++) {
            u32 w0 = Pw1[dp * 256 + o];
            m1 += bflo(w0) * lb[2 * dp] + bfhi(w0) * lb[2 * dp + 1];
        }
        if (kh) m1p[o] = m1;
        __syncthreads();
        if (!kh) t1b[o] = fmaxf(m1 + m1p[o] + bb1[o], 0.0f);
    }
    __syncthreads();
    // ---- G: mlp2: 128 outs, 4-way K split (128 mp-pairs, 32 per quad) ----
    {
        float o0 = 0.f;
        int mp0 = q * 32;
        #pragma unroll 4
        for (int mp = mp0; mp < mp0 + 32; mp++) {
            u32 w0 = Pw2[mp * 128 + h];
            o0 += bflo(w0) * t1b[2 * mp] + bfhi(w0) * t1b[2 * mp + 1];
        }
        red4w[q][h] = o0;
    }
    __syncthreads();
    float nv = 0.f;
    if (q == 0) {
        nv = hv + bb2[h] + red4w[0][h] + red4w[1][h] + red4w[2][h] + red4w[3][h];
        slots[bs * 128 + h] = nv;
        out[bs * 128 + h] = nv;
    }
    if (do_prep) {
        __syncthreads();
        // LN(slot) stats
        if (q == 0) {
            float smv = nv, sqv = nv * nv;
            for (int m = 32; m >= 1; m >>= 1) { smv += __shfl_xor(smv, m); sqv += __shfl_xor(sqv, m); }
            if ((t & 63) == 0) { red4[(t >> 6) * 2] = smv; red4[(t >> 6) * 2 + 1] = sqv; }
        }
        __syncthreads();
        float mean = (red4[0] + red4[2]) * (1.0f / 128.0f);
        float var  = (red4[1] + red4[3]) * (1.0f / 128.0f) - mean * mean;
        float rsv = rsqrtf(var + LN_EPS_);
        if (q == 0) snb[h] = (nv - mean) * rsv * g_s[h] + b_s[h];
        __syncthreads();
        // q[h] = sum_d WqT[d][h]*snb[d], 4-way (32 d per quad)
        {
            float qv = 0.f;
            int d0 = q * 32;
            #pragma unroll 4
            for (int d = d0; d < d0 + 32; d++) qv += WqT[d * 128 + h] * snb[d];
            red4w[q][h] = qv;
        }
        __syncthreads();
        if (q == 0) qb[h] = red4w[0][h] + red4w[1][h] + red4w[2][h] + red4w[3][h];
        __syncthreads();
        // r[h] = sum_j Wk[j][h]*qb[j], 4-way
        {
            float rv = 0.f;
            int j0 = q * 32;
            #pragma unroll 4
            for (int j = j0; j < j0 + 32; j++) rv += Wk[j * 128 + h] * qb[j];
            red4w[q][h] = rv;
        }
        __syncthreads();
        if (q == 0) {
            float r = (red4w[0][h] + red4w[1][h] + red4w[2][h] + red4w[3][h])
                      * 0.08838834764831845f;   // 128^-0.5
            float rt  = g_in[h] * r;
            float c2v = b_in[h] * r;
            Rg[((size_t)b * 16 + s) * 128 + h] = (u16)f2bf(rt);
            float c1p = rt, c2p = c2v;
            for (int m = 32; m >= 1; m >>= 1) { c1p += __shfl_xor(c1p, m); c2p += __shfl_xor(c2p, m); }
            if ((t & 63) == 0) { red4[(t >> 6) * 2] = c1p; red4[(t >> 6) * 2 + 1] = c2p; }
        }
        __syncthreads();
        if (t == 0) {
            c1ws[b * 8 + s] = red4[0] + red4[2];
            c2ws[b * 8 + s] = red4[1] + red4[3];
        }
    }
}

extern "C" void kernel_launch(void* const* d_in, const int* in_sizes, int n_in,
                              void* d_out, int out_size, void* d_ws, size_t ws_size,
                              hipStream_t stream) {
    const float* inputs     = (const float*)d_in[0];
    const float* slots_init = (const float*)d_in[1];
    const float* ln_in_g    = (const float*)d_in[2];
    const float* ln_in_b    = (const float*)d_in[3];
    const float* ln_s_g     = (const float*)d_in[4];
    const float* ln_s_b     = (const float*)d_in[5];
    const float* ln_m_g     = (const float*)d_in[6];
    const float* ln_m_b     = (const float*)d_in[7];
    const float* Wq         = (const float*)d_in[8];
    const float* Wk         = (const float*)d_in[9];
    const float* Wv         = (const float*)d_in[10];
    const float* W_ih       = (const float*)d_in[11];
    const float* W_hh       = (const float*)d_in[12];
    const float* b_ih       = (const float*)d_in[13];
    const float* b_hh       = (const float*)d_in[14];
    const float* mlp_w1     = (const float*)d_in[15];
    const float* mlp_b1     = (const float*)d_in[16];
    const float* mlp_w2     = (const float*)d_in[17];
    const float* mlp_b2     = (const float*)d_in[18];
    const float* slots_mu   = (const float*)d_in[19];
    const float* slots_ls   = (const float*)d_in[20];

    char* ws = (char*)d_ws;
    float* slots = (float*)(ws);                  // 229376
    u16*   Rg    = (u16*)  (ws + 229376);         // 262144 (bf16 R, 16 rows/b)
    float* c1ws  = (float*)(ws + 491520);         // 2048
    float* c2ws  = (float*)(ws + 493568);         // 2048
    float* WqT   = (float*)(ws + 495616);         // 65536
    u32*   Pv    = (u32*)  (ws + 561152);         // 32768
    u32*   Pih   = (u32*)  (ws + 593920);         // 98304
    u32*   Phh   = (u32*)  (ws + 692224);         // 98304
    u32*   Pw1   = (u32*)  (ws + 790528);         // 65536
    u32*   Pw2   = (u32*)  (ws + 856064);         // 65536
    float* Zp    = (float*)(ws + 921600);         // 131072
    float* Ap    = (float*)(ws + 1052672);        // 131072
    float* ypart = (float*)(ws + 1183744);        // 14680064 -> total ~15.9 MB

    k_pack<<<560, 256, 0, stream>>>(Wq, Wv, W_ih, W_hh, mlp_w1, mlp_w2,
                                    WqT, Pv, Pih, Phh, Pw1, Pw2, (u32*)Rg);
    k_init_prep<<<448, 256, 0, stream>>>(slots_init, slots_mu, slots_ls, slots,
                                         ln_s_g, ln_s_b, WqT, Wk, ln_in_g, ln_in_b,
                                         Rg, c1ws, c2ws);
    for (int it = 0; it < 3; it++) {
        k_attn<<<dim3(64, 64), 256, 0, stream>>>(inputs, Rg, c1ws, c2ws,
                                                 ypart, Zp, Ap);
        k_update<<<448, 512, 0, stream>>>(slots, ypart, Zp, Ap, ln_in_g, ln_in_b,
                                          Pv, Pih, Phh, b_ih, b_hh,
                                          ln_m_g, ln_m_b, Pw1, mlp_b1, Pw2, mlp_b2,
                                          (float*)d_out,
                                          ln_s_g, ln_s_b, WqT, Wk,
                                          Rg, c1ws, c2ws, (it < 2) ? 1 : 0);
    }
}